// Round 1
// baseline (124.595 us; speedup 1.0000x reference)
//
#include <hip/hip_runtime.h>

#define BATCH 4
#define IMH 96
#define IMW 96
#define NPIX (IMH * IMW)          // 9216
#define CHUNKS (NPIX / 256)       // 36

// --- block-wide sum reduction; result valid on thread 0 only ---
__device__ __forceinline__ float block_reduce_sum(float v, float* smem) {
    int lane = threadIdx.x & 63;
    int wid  = threadIdx.x >> 6;
    #pragma unroll
    for (int o = 32; o > 0; o >>= 1) v += __shfl_down(v, o, 64);
    if (lane == 0) smem[wid] = v;
    __syncthreads();
    float r = 0.f;
    if (threadIdx.x == 0) {
        int nw = blockDim.x >> 6;
        for (int w = 0; w < nw; ++w) r += smem[w];
    }
    __syncthreads();
    return r;
}

// --- Kernel A: per-image dice sums + focal partial. grid = BATCH blocks ---
__global__ void stats_kernel(const float* __restrict__ pred,
                             const float* __restrict__ target,
                             float* __restrict__ ws) {
    __shared__ float smem[8];
    int b = blockIdx.x;
    const float* p = pred + b * NPIX;
    const float* t = target + b * NPIX;
    float inter = 0.f, psum = 0.f, tsum = 0.f, inter_e = 0.f, tesum = 0.f, fsum = 0.f;
    for (int i = threadIdx.x; i < NPIX; i += blockDim.x) {
        int y = i / IMW, x = i - y * IMW;
        float tv = t[i], pv = p[i];
        float prob = 1.f / (1.f + expf(-pv));
        // 3x3 Laplacian, zero (SAME) padding
        float lap = -4.f * tv;
        lap += (y > 0)       ? t[i - IMW] : 0.f;
        lap += (y < IMH - 1) ? t[i + IMW] : 0.f;
        lap += (x > 0)       ? t[i - 1]   : 0.f;
        lap += (x < IMW - 1) ? t[i + 1]   : 0.f;
        float em = (lap != 0.f) ? 1.f : 0.f;   // |edge| > 0, integer-valued -> exact
        inter   += prob * tv;
        psum    += prob;
        tsum    += tv;
        inter_e += prob * em;
        tesum   += em;
        // stable BCE with logits
        float ce = fmaxf(pv, 0.f) - pv * tv + log1pf(expf(-fabsf(pv)));
        float pt = prob * tv + (1.f - prob) * (1.f - tv);
        float om = 1.f - pt;
        float focal = 0.25f * om * om * ce;
        fsum += (1.f + 3.f * em) * focal;
    }
    float r;
    r = block_reduce_sum(inter,   smem); if (threadIdx.x == 0) ws[b * 8 + 0] = r;
    r = block_reduce_sum(psum,    smem); if (threadIdx.x == 0) ws[b * 8 + 1] = r;
    r = block_reduce_sum(tsum,    smem); if (threadIdx.x == 0) ws[b * 8 + 2] = r;
    r = block_reduce_sum(inter_e, smem); if (threadIdx.x == 0) ws[b * 8 + 3] = r;
    r = block_reduce_sum(tesum,   smem); if (threadIdx.x == 0) ws[b * 8 + 4] = r;
    r = block_reduce_sum(fsum,    smem); if (threadIdx.x == 0) ws[b * 8 + 5] = r;
}

// --- Kernel B: soft-Hausdorff ~ exact nearest-target distance (temp=0.01,
//     integer d^2 => softmax == argmin to ~1e-40). grid = BATCH*CHUNKS blocks ---
__global__ void hausdorff_kernel(const float* __restrict__ pred,
                                 const float* __restrict__ target,
                                 float* __restrict__ ws) {
    __shared__ unsigned int s_coords[NPIX];
    __shared__ unsigned int s_cnt;
    __shared__ float smem[8];
    int b = blockIdx.x / CHUNKS;
    int chunk = blockIdx.x - b * CHUNKS;
    const float* t = target + b * NPIX;
    if (threadIdx.x == 0) s_cnt = 0u;
    __syncthreads();
    // ballot-compact target coordinates into LDS (order irrelevant for min)
    for (int i = threadIdx.x; i < NPIX; i += blockDim.x) {   // 36 uniform iters
        float tv = t[i];
        bool pos = tv > 0.5f;
        unsigned long long mask = __ballot(pos);
        int lane = threadIdx.x & 63;
        unsigned int prefix = (unsigned int)__popcll(mask & ((1ull << lane) - 1ull));
        unsigned int total  = (unsigned int)__popcll(mask);
        unsigned int base = 0u;
        if (lane == 0) base = atomicAdd(&s_cnt, total);
        base = __shfl(base, 0, 64);
        if (pos) {
            int y = i / IMW, x = i - y * IMW;
            s_coords[base + prefix] = ((unsigned int)y << 16) | (unsigned int)x;
        }
    }
    __syncthreads();
    int cnt = (int)s_cnt;
    int pix = chunk * 256 + (int)threadIdx.x;
    int py = pix / IMW, px = pix - py * IMW;
    int m0 = 0x7fffffff, m1 = 0x7fffffff, m2 = 0x7fffffff, m3 = 0x7fffffff;
    int j = 0;
    for (; j + 3 < cnt; j += 4) {
        unsigned int c0 = s_coords[j + 0];
        unsigned int c1 = s_coords[j + 1];
        unsigned int c2 = s_coords[j + 2];
        unsigned int c3 = s_coords[j + 3];
        int dx, dy;
        dx = px - (int)(c0 & 0xffffu); dy = py - (int)(c0 >> 16); m0 = min(m0, dx * dx + dy * dy);
        dx = px - (int)(c1 & 0xffffu); dy = py - (int)(c1 >> 16); m1 = min(m1, dx * dx + dy * dy);
        dx = px - (int)(c2 & 0xffffu); dy = py - (int)(c2 >> 16); m2 = min(m2, dx * dx + dy * dy);
        dx = px - (int)(c3 & 0xffffu); dy = py - (int)(c3 >> 16); m3 = min(m3, dx * dx + dy * dy);
    }
    for (; j < cnt; ++j) {
        unsigned int c0 = s_coords[j];
        int dx = px - (int)(c0 & 0xffffu);
        int dy = py - (int)(c0 >> 16);
        m0 = min(m0, dx * dx + dy * dy);
    }
    int mind = min(min(m0, m1), min(m2, m3));
    // loss_t term is identically 0 (diagonal of dists_sq); per-item guard on any-target
    float val = (cnt > 0) ? pred[b * NPIX + pix] * (float)mind : 0.f;
    float r = block_reduce_sum(val, smem);
    if (threadIdx.x == 0) ws[32 + blockIdx.x] = r;
}

// --- Kernel C: combine everything into the scalar loss ---
__global__ void finalize_kernel(const float* __restrict__ ws, float* __restrict__ out) {
    if (threadIdx.x == 0 && blockIdx.x == 0) {
        float dice_all_sum = 0.f, dice_e_sum = 0.f, te_total = 0.f, fsum = 0.f;
        for (int b = 0; b < BATCH; ++b) {
            float inter   = ws[b * 8 + 0];
            float psum    = ws[b * 8 + 1];
            float tsum    = ws[b * 8 + 2];
            float inter_e = ws[b * 8 + 3];
            float tesum   = ws[b * 8 + 4];
            fsum += ws[b * 8 + 5];
            dice_all_sum += (2.f * inter + 1e-5f) / (psum + tsum + 1e-5f);
            dice_e_sum   += (2.f * inter_e + 1e-5f) / (inter_e + tesum + 1e-5f);
            te_total += tesum;
        }
        float loss_all  = 1.f - dice_all_sum * 0.25f;
        float loss_edge = (te_total > 0.f) ? (1.f - dice_e_sum * 0.25f) : 0.f;
        float dice_loss = loss_all + 2.0f * loss_edge;
        float focal_loss = fsum / (float)(BATCH * NPIX);
        float hd = 0.f;
        for (int i = 0; i < BATCH * CHUNKS; ++i) hd += ws[32 + i];
        float hd_loss = hd * 0.25f;
        out[0] = 1.0f * dice_loss + 0.5f * focal_loss + 0.1f * hd_loss;
    }
}

extern "C" void kernel_launch(void* const* d_in, const int* in_sizes, int n_in,
                              void* d_out, int out_size, void* d_ws, size_t ws_size,
                              hipStream_t stream) {
    const float* pred   = (const float*)d_in[0];
    const float* target = (const float*)d_in[1];
    float* out = (float*)d_out;
    float* ws  = (float*)d_ws;   // needs (32 + 144) floats = 704 B

    hipLaunchKernelGGL(stats_kernel,     dim3(BATCH),          dim3(256), 0, stream, pred, target, ws);
    hipLaunchKernelGGL(hausdorff_kernel, dim3(BATCH * CHUNKS), dim3(256), 0, stream, pred, target, ws);
    hipLaunchKernelGGL(finalize_kernel,  dim3(1),              dim3(64),  0, stream, ws, out);
}

// Round 2
// 15.070 us; speedup vs baseline: 8.2679x; 8.2679x over previous
//
#include <hip/hip_runtime.h>

#define BATCH 4
#define IMH 96
#define IMW 96
#define NPIX (IMH * IMW)          // 9216
#define CHUNKS (NPIX / 256)       // 36 blocks per image
#define NBLK (BATCH * CHUNKS)     // 144

// --- block-wide sum reduction; result valid on thread 0 only ---
__device__ __forceinline__ float block_reduce_sum(float v, float* smem) {
    int lane = threadIdx.x & 63;
    int wid  = threadIdx.x >> 6;
    #pragma unroll
    for (int o = 32; o > 0; o >>= 1) v += __shfl_down(v, o, 64);
    if (lane == 0) smem[wid] = v;
    __syncthreads();
    float r = 0.f;
    if (threadIdx.x == 0) {
        #pragma unroll
        for (int w = 0; w < 4; ++w) r += smem[w];
    }
    __syncthreads();
    return r;
}

// --- Fused per-pixel kernel: dice/focal stats + exact nearest-target d^2 via
//     expanding-ring search (temp=0.01 + integer d^2 => softmax == argmin).
//     grid = NBLK blocks x 256 threads, 1 thread : 1 pixel ---
__global__ void fused_kernel(const float* __restrict__ pred,
                             const float* __restrict__ target,
                             float* __restrict__ ws) {
    __shared__ float smem[4];
    int blk   = blockIdx.x;
    int b     = blk / CHUNKS;
    int chunk = blk - b * CHUNKS;
    const float* p = pred + b * NPIX;
    const float* t = target + b * NPIX;

    int i  = chunk * 256 + (int)threadIdx.x;
    int py = i / IMW, px = i - py * IMW;
    float tv = t[i], pv = p[i];
    float prob = 1.f / (1.f + expf(-pv));

    // 3x3 Laplacian, zero (SAME) padding; |lap|>0 exact for integer masks
    float lap = -4.f * tv;
    lap += (py > 0)       ? t[i - IMW] : 0.f;
    lap += (py < IMH - 1) ? t[i + IMW] : 0.f;
    lap += (px > 0)       ? t[i - 1]   : 0.f;
    lap += (px < IMW - 1) ? t[i + 1]   : 0.f;
    float em = (lap != 0.f) ? 1.f : 0.f;

    // stable BCE-with-logits + focal, pre-weighted by boundary factor
    float ce = fmaxf(pv, 0.f) - pv * tv + log1pf(expf(-fabsf(pv)));
    float pt = prob * tv + (1.f - prob) * (1.f - tv);
    float om = 1.f - pt;
    float fsum = (1.f + 3.f * em) * (0.25f * om * om * ce);

    // ---- expanding-ring exact nearest-target squared distance ----
    int best = (tv > 0.5f) ? 0 : 0x7fffffff;
    for (int r = 1; r <= 95; ++r) {
        int rr = r * r;
        if (__all(best <= rr)) break;         // wave-uniform early exit
        if (best > rr) {                      // lane-level predication
            int y0 = py - r, y1 = py + r, x0 = px - r, x1 = px + r;
            // top & bottom rows of the ring (coalesced across lanes)
            for (int xx = x0; xx <= x1; ++xx) {
                if ((unsigned)xx < (unsigned)IMW) {
                    int dx = xx - px, dd = dx * dx + rr;
                    if ((unsigned)y0 < (unsigned)IMH && t[y0 * IMW + xx] > 0.5f) best = min(best, dd);
                    if ((unsigned)y1 < (unsigned)IMH && t[y1 * IMW + xx] > 0.5f) best = min(best, dd);
                }
            }
            // left & right columns (excluding corners)
            for (int yy = y0 + 1; yy <= y1 - 1; ++yy) {
                if ((unsigned)yy < (unsigned)IMH) {
                    int dy = yy - py, dd = dy * dy + rr;
                    if ((unsigned)x0 < (unsigned)IMW && t[yy * IMW + x0] > 0.5f) best = min(best, dd);
                    if ((unsigned)x1 < (unsigned)IMW && t[yy * IMW + x1] > 0.5f) best = min(best, dd);
                }
            }
        }
    }
    // no-target image => best stays INT_MAX => contributes 0 (matches where(m.any(),...))
    float hd_val = (best == 0x7fffffff) ? 0.f : pv * (float)best;

    float* wsb = ws + blk * 8;
    float r;
    r = block_reduce_sum(prob * tv, smem); if (threadIdx.x == 0) wsb[0] = r;
    r = block_reduce_sum(prob,      smem); if (threadIdx.x == 0) wsb[1] = r;
    r = block_reduce_sum(tv,        smem); if (threadIdx.x == 0) wsb[2] = r;
    r = block_reduce_sum(prob * em, smem); if (threadIdx.x == 0) wsb[3] = r;
    r = block_reduce_sum(em,        smem); if (threadIdx.x == 0) wsb[4] = r;
    r = block_reduce_sum(fsum,      smem); if (threadIdx.x == 0) wsb[5] = r;
    r = block_reduce_sum(hd_val,    smem); if (threadIdx.x == 0) wsb[6] = r;
}

// --- Finalize: wave w reduces image w's 36 block-partials; thread 0 combines ---
__global__ void finalize_kernel(const float* __restrict__ ws, float* __restrict__ out) {
    __shared__ float simg[BATCH][8];
    int tid  = threadIdx.x;
    int wid  = tid >> 6;       // image index
    int lane = tid & 63;
    float v0 = 0.f, v1 = 0.f, v2 = 0.f, v3 = 0.f, v4 = 0.f, v5 = 0.f, v6 = 0.f;
    if (lane < CHUNKS) {
        const float* w = ws + (wid * CHUNKS + lane) * 8;
        v0 = w[0]; v1 = w[1]; v2 = w[2]; v3 = w[3]; v4 = w[4]; v5 = w[5]; v6 = w[6];
    }
    #pragma unroll
    for (int o = 32; o > 0; o >>= 1) {
        v0 += __shfl_down(v0, o, 64); v1 += __shfl_down(v1, o, 64);
        v2 += __shfl_down(v2, o, 64); v3 += __shfl_down(v3, o, 64);
        v4 += __shfl_down(v4, o, 64); v5 += __shfl_down(v5, o, 64);
        v6 += __shfl_down(v6, o, 64);
    }
    if (lane == 0) {
        simg[wid][0] = v0; simg[wid][1] = v1; simg[wid][2] = v2; simg[wid][3] = v3;
        simg[wid][4] = v4; simg[wid][5] = v5; simg[wid][6] = v6;
    }
    __syncthreads();
    if (tid == 0) {
        float dice_all_sum = 0.f, dice_e_sum = 0.f, te_total = 0.f, fsum = 0.f, hd = 0.f;
        for (int b = 0; b < BATCH; ++b) {
            float inter   = simg[b][0];
            float psum    = simg[b][1];
            float tsum    = simg[b][2];
            float inter_e = simg[b][3];
            float tesum   = simg[b][4];
            fsum += simg[b][5];
            hd   += simg[b][6];
            dice_all_sum += (2.f * inter + 1e-5f) / (psum + tsum + 1e-5f);
            dice_e_sum   += (2.f * inter_e + 1e-5f) / (inter_e + tesum + 1e-5f);
            te_total += tesum;
        }
        float loss_all  = 1.f - dice_all_sum * 0.25f;
        float loss_edge = (te_total > 0.f) ? (1.f - dice_e_sum * 0.25f) : 0.f;
        float dice_loss = loss_all + 2.0f * loss_edge;
        float focal_loss = fsum / (float)(BATCH * NPIX);
        float hd_loss = hd * 0.25f;
        out[0] = 1.0f * dice_loss + 0.5f * focal_loss + 0.1f * hd_loss;
    }
}

extern "C" void kernel_launch(void* const* d_in, const int* in_sizes, int n_in,
                              void* d_out, int out_size, void* d_ws, size_t ws_size,
                              hipStream_t stream) {
    const float* pred   = (const float*)d_in[0];
    const float* target = (const float*)d_in[1];
    float* out = (float*)d_out;
    float* ws  = (float*)d_ws;   // needs NBLK*8 floats = 4608 B

    hipLaunchKernelGGL(fused_kernel,    dim3(NBLK), dim3(256), 0, stream, pred, target, ws);
    hipLaunchKernelGGL(finalize_kernel, dim3(1),    dim3(256), 0, stream, ws, out);
}

// Round 3
// 12.812 us; speedup vs baseline: 9.7250x; 1.1762x over previous
//
#include <hip/hip_runtime.h>

#define BATCH 4
#define IMH 96
#define IMW 96
#define NPIX (IMH * IMW)          // 9216
#define CHUNKS (NPIX / 256)       // 36 blocks per image
#define NBLK (BATCH * CHUNKS)     // 144

// --- Fused per-pixel kernel: dice/focal stats + exact nearest-target d^2.
//     5x5 window covers d^2<=8; ring-3 min d^2 is 9, so __all(best<=9) proves
//     exactness. Generic ring fallback kept for the 2^-25 case / no-target.
//     grid = NBLK x 256, 1 thread : 1 pixel ---
__global__ void __launch_bounds__(256) fused_kernel(const float* __restrict__ pred,
                                                    const float* __restrict__ target,
                                                    float* __restrict__ ws) {
    __shared__ float smem[4][8];
    int blk   = blockIdx.x;
    int b     = blk / CHUNKS;
    int chunk = blk - b * CHUNKS;
    const float* p = pred + b * NPIX;
    const float* t = target + b * NPIX;

    int i  = chunk * 256 + (int)threadIdx.x;
    int py = i / IMW, px = i - py * IMW;
    float pv = p[i];

    // ---- one-shot 5x5 neighborhood load (OOB -> 0), all loads independent ----
    float w[5][5];
    #pragma unroll
    for (int dy = -2; dy <= 2; ++dy) {
        int yy = py + dy;
        bool yok = (unsigned)yy < (unsigned)IMH;
        #pragma unroll
        for (int dx = -2; dx <= 2; ++dx) {
            int xx = px + dx;
            bool ok = yok && ((unsigned)xx < (unsigned)IMW);
            w[dy + 2][dx + 2] = ok ? t[yy * IMW + xx] : 0.f;
        }
    }
    float tv = w[2][2];

    // 3x3 Laplacian from window registers (zero SAME padding matches OOB=0)
    float lap = w[1][2] + w[3][2] + w[2][1] + w[2][3] - 4.f * tv;
    float em  = (lap != 0.f) ? 1.f : 0.f;

    float prob = 1.f / (1.f + expf(-pv));
    float ce = fmaxf(pv, 0.f) - pv * tv + log1pf(expf(-fabsf(pv)));
    float pt = prob * tv + (1.f - prob) * (1.f - tv);
    float om = 1.f - pt;
    float fsum = (1.f + 3.f * em) * (0.25f * om * om * ce);

    // ---- nearest-target squared distance: window min, then rare fallback ----
    int best = 0x7fffffff;
    #pragma unroll
    for (int dy = -2; dy <= 2; ++dy)
        #pragma unroll
        for (int dx = -2; dx <= 2; ++dx)
            if (w[dy + 2][dx + 2] > 0.5f) best = min(best, dy * dy + dx * dx);

    if (!__all(best <= 9)) {               // cold path: P ~= 64 * 2^-25 per wave
        for (int r = 3; r <= 95; ++r) {
            int rr = r * r;
            if (__all(best <= rr)) break;
            if (best > rr) {
                int y0 = py - r, y1 = py + r, x0 = px - r, x1 = px + r;
                for (int xx = x0; xx <= x1; ++xx) {
                    if ((unsigned)xx < (unsigned)IMW) {
                        int dx = xx - px, dd = dx * dx + rr;
                        if ((unsigned)y0 < (unsigned)IMH && t[y0 * IMW + xx] > 0.5f) best = min(best, dd);
                        if ((unsigned)y1 < (unsigned)IMH && t[y1 * IMW + xx] > 0.5f) best = min(best, dd);
                    }
                }
                for (int yy = y0 + 1; yy <= y1 - 1; ++yy) {
                    if ((unsigned)yy < (unsigned)IMH) {
                        int dy = yy - py, dd = dy * dy + rr;
                        if ((unsigned)x0 < (unsigned)IMW && t[yy * IMW + x0] > 0.5f) best = min(best, dd);
                        if ((unsigned)x1 < (unsigned)IMW && t[yy * IMW + x1] > 0.5f) best = min(best, dd);
                    }
                }
            }
        }
    }
    // no-target image => best stays INT_MAX => contributes 0 (matches where(m.any(),...))
    float hd_val = (best == 0x7fffffff) ? 0.f : pv * (float)best;

    // ---- packed 7-way block reduction: 6 shuffle rounds + ONE barrier ----
    float vals[7] = { prob * tv, prob, tv, prob * em, em, fsum, hd_val };
    int lane = threadIdx.x & 63;
    int wid  = threadIdx.x >> 6;
    #pragma unroll
    for (int o = 32; o > 0; o >>= 1) {
        #pragma unroll
        for (int k = 0; k < 7; ++k) vals[k] += __shfl_down(vals[k], o, 64);
    }
    if (lane == 0) {
        #pragma unroll
        for (int k = 0; k < 7; ++k) smem[wid][k] = vals[k];
    }
    __syncthreads();
    if (threadIdx.x == 0) {
        float* wsb = ws + blk * 8;
        #pragma unroll
        for (int k = 0; k < 7; ++k)
            wsb[k] = smem[0][k] + smem[1][k] + smem[2][k] + smem[3][k];
    }
}

// --- Finalize: wave w reduces image w's 36 block-partials; thread 0 combines ---
__global__ void __launch_bounds__(256) finalize_kernel(const float* __restrict__ ws,
                                                       float* __restrict__ out) {
    __shared__ float simg[BATCH][8];
    int tid  = threadIdx.x;
    int wid  = tid >> 6;       // image index
    int lane = tid & 63;
    float v[7] = {0.f, 0.f, 0.f, 0.f, 0.f, 0.f, 0.f};
    if (lane < CHUNKS) {
        const float* w = ws + (wid * CHUNKS + lane) * 8;
        #pragma unroll
        for (int k = 0; k < 7; ++k) v[k] = w[k];
    }
    #pragma unroll
    for (int o = 32; o > 0; o >>= 1) {
        #pragma unroll
        for (int k = 0; k < 7; ++k) v[k] += __shfl_down(v[k], o, 64);
    }
    if (lane == 0) {
        #pragma unroll
        for (int k = 0; k < 7; ++k) simg[wid][k] = v[k];
    }
    __syncthreads();
    if (tid == 0) {
        float dice_all_sum = 0.f, dice_e_sum = 0.f, te_total = 0.f, fsum = 0.f, hd = 0.f;
        for (int b = 0; b < BATCH; ++b) {
            float inter   = simg[b][0];
            float psum    = simg[b][1];
            float tsum    = simg[b][2];
            float inter_e = simg[b][3];
            float tesum   = simg[b][4];
            fsum += simg[b][5];
            hd   += simg[b][6];
            dice_all_sum += (2.f * inter + 1e-5f) / (psum + tsum + 1e-5f);
            dice_e_sum   += (2.f * inter_e + 1e-5f) / (inter_e + tesum + 1e-5f);
            te_total += tesum;
        }
        float loss_all  = 1.f - dice_all_sum * 0.25f;
        float loss_edge = (te_total > 0.f) ? (1.f - dice_e_sum * 0.25f) : 0.f;
        float dice_loss = loss_all + 2.0f * loss_edge;
        float focal_loss = fsum / (float)(BATCH * NPIX);
        float hd_loss = hd * 0.25f;
        out[0] = 1.0f * dice_loss + 0.5f * focal_loss + 0.1f * hd_loss;
    }
}

extern "C" void kernel_launch(void* const* d_in, const int* in_sizes, int n_in,
                              void* d_out, int out_size, void* d_ws, size_t ws_size,
                              hipStream_t stream) {
    const float* pred   = (const float*)d_in[0];
    const float* target = (const float*)d_in[1];
    float* out = (float*)d_out;
    float* ws  = (float*)d_ws;   // needs NBLK*8 floats = 4608 B

    hipLaunchKernelGGL(fused_kernel,    dim3(NBLK), dim3(256), 0, stream, pred, target, ws);
    hipLaunchKernelGGL(finalize_kernel, dim3(1),    dim3(256), 0, stream, ws, out);
}